// Round 4
// baseline (286.478 us; speedup 1.0000x reference)
//
#include <hip/hip_runtime.h>
#include <math.h>

// Problem geometry (fixed by the reference): _p,_q are (8192, 4096) f32.
constexpr int ROWS = 8192;
constexpr int COLS = 4096;
constexpr int TPB  = 256;              // 4 waves per block
constexpr int WAVES = TPB / 64;
constexpr int EPT  = COLS / TPB;       // 16 elements per thread, as 4x float4

__device__ __forceinline__ float wave_sum(float v) {
    #pragma unroll
    for (int o = 32; o > 0; o >>= 1) v += __shfl_xor(v, o, 64);
    return v;
}

__device__ __forceinline__ float wave_max(float v) {
    #pragma unroll
    for (int o = 32; o > 0; o >>= 1) v = fmaxf(v, __shfl_xor(v, o, 64));
    return v;
}

__device__ __forceinline__ float block_sum(float v, float* smem, int tid) {
    v = wave_sum(v);
    const int wid = tid >> 6, lane = tid & 63;
    if (lane == 0) smem[wid] = v;
    __syncthreads();
    if (wid == 0) {
        float x = (lane < WAVES) ? smem[lane] : 0.0f;
        x = wave_sum(x);
        if (lane == 0) smem[0] = x;
    }
    __syncthreads();
    const float r = smem[0];
    __syncthreads();   // smem is reused by the next reduction
    return r;
}

__device__ __forceinline__ float block_max(float v, float* smem, int tid) {
    v = wave_max(v);
    const int wid = tid >> 6, lane = tid & 63;
    if (lane == 0) smem[wid] = v;
    __syncthreads();
    if (wid == 0) {
        float x = (lane < WAVES) ? smem[lane] : -INFINITY;
        x = wave_max(x);
        if (lane == 0) smem[0] = x;
    }
    __syncthreads();
    const float r = smem[0];
    __syncthreads();
    return r;
}

// One block per row. Single pass over HBM: row held in registers.
__global__ __launch_bounds__(TPB) void wjs_row_kernel(const float* __restrict__ P,
                                                      const float* __restrict__ Q,
                                                      float* __restrict__ rowres) {
    __shared__ float smem[WAVES];
    const int row = blockIdx.x;
    const int tid = threadIdx.x;
    const float* __restrict__ prow = P + (size_t)row * COLS;
    const float* __restrict__ qrow = Q + (size_t)row * COLS;

    // Coalesced float4 loads: lane i takes columns [c*1024 + 4*i, +4).
    float vp[EPT], vq[EPT];
    #pragma unroll
    for (int c = 0; c < EPT / 4; ++c) {
        const int col = c * (TPB * 4) + tid * 4;
        const float4 a = *reinterpret_cast<const float4*>(prow + col);
        const float4 b = *reinterpret_cast<const float4*>(qrow + col);
        vp[4*c+0] = a.x; vp[4*c+1] = a.y; vp[4*c+2] = a.z; vp[4*c+3] = a.w;
        vq[4*c+0] = b.x; vq[4*c+1] = b.y; vq[4*c+2] = b.z; vq[4*c+3] = b.w;
    }

    // Row maxima for both distributions.
    float mp = -INFINITY, mq = -INFINITY;
    #pragma unroll
    for (int i = 0; i < EPT; ++i) { mp = fmaxf(mp, vp[i]); mq = fmaxf(mq, vq[i]); }
    mp = block_max(mp, smem, tid);
    mq = block_max(mq, smem, tid);

    // exp(x - max), kept in registers; row sums.
    float ep[EPT], eq[EPT];
    float sp = 0.0f, sq = 0.0f;
    #pragma unroll
    for (int i = 0; i < EPT; ++i) {
        ep[i] = __expf(vp[i] - mp); sp += ep[i];
        eq[i] = __expf(vq[i] - mq); sq += eq[i];
    }
    sp = block_sum(sp, smem, tid);
    sq = block_sum(sq, smem, tid);

    const float inv_sp = 1.0f / sp;
    const float inv_sq = 1.0f / sq;
    const float lsp = __logf(sp);
    const float lsq = __logf(sq);

    // jsd_j = 0.5*( q*(log q - log m) + p*(log p - log m) ), m = (p+q)/2
    // log p_j = (x_j - max) - log(sum)  -- no per-element log for p,q.
    float acc = 0.0f;
    #pragma unroll
    for (int i = 0; i < EPT; ++i) {
        const float p  = ep[i] * inv_sp;
        const float q  = eq[i] * inv_sq;
        const float m  = 0.5f * (p + q);
        const float lm = __logf(m);
        const float lp = (vp[i] - mp) - lsp;
        const float lq = (vq[i] - mq) - lsq;
        const float jsd = 0.5f * (q * (lq - lm) + p * (lp - lm));
        const float d  = vp[i] - vq[i];
        acc = fmaf(d * d, jsd, acc);
    }
    acc = block_sum(acc, smem, tid);
    if (tid == 0) rowres[row] = sqrtf(fmaxf(acc, 0.0f));  // clamp rounding negatives
}

// Deterministic final sum over the 8192 per-row results. Fully writes d_out.
__global__ __launch_bounds__(TPB) void wjs_final_kernel(const float* __restrict__ rowres,
                                                        float* __restrict__ out) {
    __shared__ float smem[WAVES];
    float acc = 0.0f;
    for (int i = threadIdx.x; i < ROWS; i += TPB) acc += rowres[i];
    acc = block_sum(acc, smem, threadIdx.x);
    if (threadIdx.x == 0) out[0] = acc;
}

extern "C" void kernel_launch(void* const* d_in, const int* in_sizes, int n_in,
                              void* d_out, int out_size, void* d_ws, size_t ws_size,
                              hipStream_t stream) {
    const float* P = (const float*)d_in[0];
    const float* Q = (const float*)d_in[1];
    float* rowres  = (float*)d_ws;        // 8192 floats = 32 KB scratch
    float* out     = (float*)d_out;

    wjs_row_kernel<<<ROWS, TPB, 0, stream>>>(P, Q, rowres);
    wjs_final_kernel<<<1, TPB, 0, stream>>>(rowres, out);
}